// Round 6
// baseline (511.552 us; speedup 1.0000x reference)
//
#include <hip/hip_runtime.h>
#include <hip/hip_bf16.h>
#include <stdint.h>

typedef unsigned short u16;
typedef __bf16 bf16x8 __attribute__((ext_vector_type(8)));
typedef __attribute__((ext_vector_type(4))) float f32x4;
typedef __attribute__((ext_vector_type(16))) float f32x16;
typedef __attribute__((ext_vector_type(4))) unsigned short u16x4;
typedef __attribute__((ext_vector_type(4))) int i32x4;

#define T_ 2048

__device__ __forceinline__ u16 f2bf(float f) {
  __hip_bfloat16 h = __float2bfloat16(f);
  return __builtin_bit_cast(u16, h);
}
__device__ __forceinline__ float bf2f(u16 u) {
  __hip_bfloat16 h = __builtin_bit_cast(__hip_bfloat16, u);
  return __bfloat162float(h);
}
__device__ __forceinline__ unsigned pk2(float a, float b) {
  return (unsigned)f2bf(a) | ((unsigned)f2bf(b) << 16);
}

// ---------------- casts ----------------
__global__ __launch_bounds__(256) void cast_f32_bf16(const float* __restrict__ in,
                                                     u16* __restrict__ outp, int n) {
  int i = (blockIdx.x * 256 + threadIdx.x) * 4;
  if (i < n) {
    f32x4 v = *(const f32x4*)(in + i);
    u16x4 o;
    o.x = f2bf(v.x); o.y = f2bf(v.y); o.z = f2bf(v.z); o.w = f2bf(v.w);
    *(u16x4*)(outp + i) = o;
  }
}

// in fp32 [R][C] -> out bf16 [Cpad][R]; cols >= C write 0 (zero padding rows).
__global__ __launch_bounds__(256) void castT(const float* __restrict__ in,
                                             u16* __restrict__ outp, int R, int C) {
  __shared__ float tile[32][33];
  int tx = threadIdx.x & 31, ty = threadIdx.x >> 5;
  int r0 = blockIdx.y * 32, c0 = blockIdx.x * 32;
#pragma unroll
  for (int p = 0; p < 4; p++) {
    int rr = r0 + ty + p * 8;
    int cc = c0 + tx;
    tile[ty + p * 8][tx] = (cc < C) ? in[(size_t)rr * C + cc] : 0.f;
  }
  __syncthreads();
#pragma unroll
  for (int p = 0; p < 4; p++) {
    outp[(size_t)(c0 + ty + p * 8) * R + r0 + tx] = f2bf(tile[tx][ty + p * 8]);
  }
}

// ---------------- rmsnorm over rows ----------------
__global__ __launch_bounds__(256) void rmsnorm_rows(const u16* __restrict__ in,
                                                    u16* __restrict__ outp,
                                                    const float* __restrict__ w,
                                                    int D, int sin, int sout) {
  int r = blockIdx.x, tid = threadIdx.x;
  int wave = tid >> 6, lane = tid & 63;
  __shared__ float sred[4];
  float vals[6];
  int E = D >> 8;
  float ss = 0.f;
  for (int e = 0; e < E; e++) {
    float v = bf2f(in[(size_t)r * sin + e * 256 + tid]);
    vals[e] = v;
    ss += v * v;
  }
#pragma unroll
  for (int d = 1; d < 64; d <<= 1) ss += __shfl_xor(ss, d, 64);
  if (lane == 0) sred[wave] = ss;
  __syncthreads();
  ss = sred[0] + sred[1] + sred[2] + sred[3];
  float rr = rsqrtf(ss / (float)D + 1e-6f);
  for (int e = 0; e < E; e++)
    outp[(size_t)r * sout + e * 256 + tid] = f2bf(vals[e] * rr * w[e * 256 + tid]);
}

// ---------------- GEMM: C[M,N] = A[M,K] * Bt[N,K]^T  (bf16 in, fp32 acc) ----
// BK=64, register-prefetch double-buffer, XOR-swizzled LDS (chunk ^ (row&7)).
__global__ __launch_bounds__(256) void gemm_bt(const u16* __restrict__ A,
                                               const u16* __restrict__ Bt,
                                               void* __restrict__ Cv,
                                               int M, int N, int K, int cf32) {
  __shared__ u16 As[128 * 64];
  __shared__ u16 Bs[128 * 64];
  const int tid = threadIdx.x;
  const int wave = tid >> 6, lane = tid & 63;
  const int m0 = blockIdx.y * 128, n0 = blockIdx.x * 128;
  const int wm = (wave >> 1) * 64, wn = (wave & 1) * 64;
  const int fr = lane & 15, fq = lane >> 4;
  f32x4 acc[4][4] = {};

  const int srow = tid >> 1;
  const int scb = (tid & 1) * 4;
  const u16* apg = A + (size_t)(m0 + srow) * K + scb * 8;
  const u16* bpg = Bt + (size_t)(n0 + srow) * K + scb * 8;
  u16* awp[4];
  u16* bwp[4];
#pragma unroll
  for (int i = 0; i < 4; i++) {
    int sw = ((scb + i) ^ (srow & 7)) << 3;
    awp[i] = As + srow * 64 + sw;
    bwp[i] = Bs + srow * 64 + sw;
  }
  const u16* ard[2][4];
  const u16* brd[2][4];
#pragma unroll
  for (int ks = 0; ks < 2; ks++)
#pragma unroll
    for (int i = 0; i < 4; i++) {
      int ra = wm + 16 * i + fr;
      ard[ks][i] = As + ra * 64 + (((fq + ks * 4) ^ (ra & 7)) << 3);
      int rb = wn + 16 * i + fr;
      brd[ks][i] = Bs + rb * 64 + (((fq + ks * 4) ^ (rb & 7)) << 3);
    }

  i32x4 areg[4], breg[4];
#pragma unroll
  for (int i = 0; i < 4; i++) {
    areg[i] = *(const i32x4*)(apg + i * 8);
    breg[i] = *(const i32x4*)(bpg + i * 8);
  }

  for (int k0 = 0; k0 < K; k0 += 64) {
    if (k0) __syncthreads();
#pragma unroll
    for (int i = 0; i < 4; i++) {
      *(i32x4*)awp[i] = areg[i];
      *(i32x4*)bwp[i] = breg[i];
    }
    __syncthreads();
    if (k0 + 64 < K) {
#pragma unroll
      for (int i = 0; i < 4; i++) {
        areg[i] = *(const i32x4*)(apg + k0 + 64 + i * 8);
        breg[i] = *(const i32x4*)(bpg + k0 + 64 + i * 8);
      }
    }
#pragma unroll
    for (int ks = 0; ks < 2; ks++) {
      bf16x8 af[4], bf[4];
#pragma unroll
      for (int i = 0; i < 4; i++) {
        af[i] = *(const bf16x8*)ard[ks][i];
        bf[i] = *(const bf16x8*)brd[ks][i];
      }
#pragma unroll
      for (int i = 0; i < 4; i++)
#pragma unroll
        for (int j = 0; j < 4; j++)
          acc[i][j] = __builtin_amdgcn_mfma_f32_16x16x32_bf16(af[i], bf[j], acc[i][j], 0, 0, 0);
    }
  }
  if (cf32) {
    float* C = (float*)Cv;
#pragma unroll
    for (int i = 0; i < 4; i++)
#pragma unroll
      for (int j = 0; j < 4; j++)
#pragma unroll
        for (int r = 0; r < 4; r++)
          C[(size_t)(m0 + wm + 16 * i + fq * 4 + r) * N + n0 + wn + 16 * j + fr] = acc[i][j][r];
  } else {
    u16* C = (u16*)Cv;
#pragma unroll
    for (int i = 0; i < 4; i++)
#pragma unroll
      for (int j = 0; j < 4; j++)
#pragma unroll
        for (int r = 0; r < 4; r++)
          C[(size_t)(m0 + wm + 16 * i + fq * 4 + r) * N + n0 + wn + 16 * j + fr] = f2bf(acc[i][j][r]);
  }
}

// ---------------- q pack: head rmsnorm + rope + 1/sqrt(192) scale ----------
__global__ __launch_bounds__(256) void qpack(const u16* __restrict__ qnr,
                                             const float* __restrict__ qhw,
                                             const float* __restrict__ fcos,
                                             const float* __restrict__ fsin,
                                             u16* __restrict__ qp) {
  int gw = blockIdx.x * 4 + (threadIdx.x >> 6);
  int lane = threadIdx.x & 63;
  int r = gw >> 4, h = gw & 15;
  int b = r >> 11, t = r & 2047;
  const float sc = 0.07216878364870323f;  // 1/sqrt(192), folded into Q
  float v0 = bf2f(qnr[(size_t)r * 3072 + h * 128 + lane]);
  float v1 = bf2f(qnr[(size_t)r * 3072 + h * 128 + 64 + lane]);
  float ss = v0 * v0 + v1 * v1;
#pragma unroll
  for (int d = 1; d < 64; d <<= 1) ss += __shfl_xor(ss, d, 64);
  float rr = rsqrtf(ss * (1.f / 128.f) + 1e-6f) * sc;
  size_t ob = ((size_t)(b * 16 + h) * 2048 + t) * 192;
  qp[ob + lane] = f2bf(v0 * rr * qhw[lane]);
  qp[ob + 64 + lane] = f2bf(v1 * rr * qhw[64 + lane]);
  if (lane < 32) {
    float a = bf2f(qnr[(size_t)r * 3072 + 2048 + h * 64 + 2 * lane]);
    float bb = bf2f(qnr[(size_t)r * 3072 + 2048 + h * 64 + 2 * lane + 1]);
    float c = fcos[t * 32 + lane], s = fsin[t * 32 + lane];
    qp[ob + 128 + 2 * lane] = f2bf((a * c - bb * s) * sc);
    qp[ob + 129 + 2 * lane] = f2bf((a * s + bb * c) * sc);
  }
}

// ---------------- kv pack ----------------
__global__ __launch_bounds__(256) void kvpack(const u16* __restrict__ kvu,
                                              const u16* __restrict__ kvr,
                                              int ks,
                                              const float* __restrict__ khw,
                                              const float* __restrict__ fcos,
                                              const float* __restrict__ fsin,
                                              u16* __restrict__ kp,
                                              u16* __restrict__ vp) {
  int h = blockIdx.x & 15, tile = blockIdx.x >> 4;
  int r0 = tile * 64;
  int b = r0 >> 11;
  int tl = tile & 31;
  int tid = threadIdx.x, wave = tid >> 6, lane = tid & 63;
  __shared__ u16 vsl[128 * 66];
  int bh = b * 16 + h;
  for (int ii = 0; ii < 16; ii++) {
    int i = wave * 16 + ii;
    int r = r0 + i;
    int t = r & 2047;
    size_t kbase = (size_t)r * 4096 + h * 256;
    float v0 = bf2f(kvu[kbase + lane]);
    float v1 = bf2f(kvu[kbase + 64 + lane]);
    float ss = v0 * v0 + v1 * v1;
#pragma unroll
    for (int d = 1; d < 64; d <<= 1) ss += __shfl_xor(ss, d, 64);
    float rr = rsqrtf(ss * (1.f / 128.f) + 1e-6f);
    size_t ob = ((size_t)bh * 2048 + t) * 192;
    kp[ob + lane] = f2bf(v0 * rr * khw[lane]);
    kp[ob + 64 + lane] = f2bf(v1 * rr * khw[64 + lane]);
    vsl[lane * 66 + i] = kvu[kbase + 128 + lane];
    vsl[(lane + 64) * 66 + i] = kvu[kbase + 192 + lane];
    if (lane < 32) {
      float a = bf2f(kvr[(size_t)r * ks + 512 + 2 * lane]);
      float bb = bf2f(kvr[(size_t)r * ks + 512 + 2 * lane + 1]);
      float c = fcos[t * 32 + lane], s = fsin[t * 32 + lane];
      kp[ob + 128 + 2 * lane] = f2bf(a * c - bb * s);
      kp[ob + 129 + 2 * lane] = f2bf(a * s + bb * c);
    }
  }
  __syncthreads();
  u16* vb = vp + ((size_t)bh * 32 + tl) * 8192;  // [128 v][64 t] tile
  for (int u = 0; u < 32; u++) {
    int e = u * 256 + tid;
    vb[e] = vsl[(e >> 6) * 66 + (e & 63)];
  }
}

// ---------------- flash attention (causal), S^T formulation ----------------
// 512-thread blocks, 8 waves x 32 q = 256 q per block -> tile-reads per bh
// drop 272 -> 144 (memory-bound regime). XCD swizzle: all 8 s-blocks of a bh
// share an XCD's L2. P C->B layout transform in-register via shfl_xor(32)
// (no Ps LDS, no extra barrier). LDS 48 KB.
__global__ __launch_bounds__(512, 2) void attn_kernel(const u16* __restrict__ Q,
                                                      const u16* __restrict__ Kp,
                                                      const u16* __restrict__ Vt,
                                                      u16* __restrict__ O) {
  __shared__ u16 Ks[64 * 256];   // [64 k][24 used 16B-chunks of 32], swizzled
  __shared__ u16 Vs[128 * 64];   // [128 v][8 chunks], swizzled
  const int tid = threadIdx.x;
  const int wave = tid >> 6, lane = tid & 63;
  const int bid = blockIdx.x;
  const int bh = (bid & 7) | ((bid >> 6) << 3);     // XCD-locality swizzle
  const int s = 7 - ((bid >> 3) & 7);               // heavy super-blocks first
  const int l31 = lane & 31, half = lane >> 5, xr = lane & 7;
  const int qw0 = s * 256 + wave * 32;
  const int qg = qw0 + l31;
  const int jmax = 4 * s + 3;

  bf16x8 qf[12];
  {
    const u16* qbp = Q + ((size_t)bh * T_ + qg) * 192 + half * 8;
#pragma unroll
    for (int t = 0; t < 12; t++) qf[t] = *(const bf16x8*)(qbp + t * 16);
  }
  f32x16 oacc[4] = {};
  float m_i = -3.0e38f, l_i = 0.f;

  const char* kgb = (const char*)(Kp + (size_t)bh * T_ * 192);
  const char* vgb = (const char*)(Vt + (size_t)bh * 32 * 8192);
  u16* kw[3];
  u16* vw[2];
#pragma unroll
  for (int c = 0; c < 3; c++) {
    unsigned fo = c * 8192 + tid * 16;
    unsigned row = fo / 384u;
    unsigned chunk = (fo - row * 384) >> 4;
    kw[c] = Ks + row * 256 + ((chunk ^ (row & 7)) << 3);
  }
#pragma unroll
  for (int c = 0; c < 2; c++) {
    unsigned fo = c * 8192 + tid * 16;
    unsigned row = fo >> 7;
    unsigned chunk = (fo >> 4) & 7;
    vw[c] = Vs + row * 64 + ((chunk ^ (row & 7)) << 3);
  }
  const u16* krd0 = Ks + l31 * 256;
  const u16* krd1 = Ks + (32 + l31) * 256;
  const u16* vrd = Vs + l31 * 64;

  i32x4 kreg[3], vreg[2];
#pragma unroll
  for (int c = 0; c < 3; c++) kreg[c] = *(const i32x4*)(kgb + c * 8192 + tid * 16);
#pragma unroll
  for (int c = 0; c < 2; c++) vreg[c] = *(const i32x4*)(vgb + c * 8192 + tid * 16);

  for (int j = 0; j <= jmax; j++) {
    if (j) __syncthreads();
#pragma unroll
    for (int c = 0; c < 3; c++) *(i32x4*)kw[c] = kreg[c];
#pragma unroll
    for (int c = 0; c < 2; c++) *(i32x4*)vw[c] = vreg[c];
    __syncthreads();
    if (j < jmax) {
      const char* kg = kgb + (size_t)(j + 1) * 24576;
      const char* vg = vgb + (size_t)(j + 1) * 16384;
#pragma unroll
      for (int c = 0; c < 3; c++) kreg[c] = *(const i32x4*)(kg + c * 8192 + tid * 16);
#pragma unroll
      for (int c = 0; c < 2; c++) vreg[c] = *(const i32x4*)(vg + c * 8192 + tid * 16);
    }
    if (j * 64 > qw0 + 31) continue;  // tile fully masked for this wave

    // S^T[64k x 32q]
    f32x16 sa[2] = {};
#pragma unroll
    for (int t = 0; t < 12; t++) {
      int sl = ((2 * t + half) ^ xr) << 3;
      bf16x8 a0 = *(const bf16x8*)(krd0 + sl);
      bf16x8 a1 = *(const bf16x8*)(krd1 + sl);
      sa[0] = __builtin_amdgcn_mfma_f32_32x32x16_bf16(a0, qf[t], sa[0], 0, 0, 0);
      sa[1] = __builtin_amdgcn_mfma_f32_32x32x16_bf16(a1, qf[t], sa[1], 0, 0, 0);
    }
    if (j * 64 + 63 > qw0) {
      int kb = j * 64 + 4 * half;
#pragma unroll
      for (int tt = 0; tt < 2; tt++)
#pragma unroll
        for (int r = 0; r < 16; r++) {
          int kk = kb + tt * 32 + (r & 3) + 8 * (r >> 2);
          if (kk > qg) sa[tt][r] = -3.0e38f;
        }
    }
    float mx = -3.0e38f;
#pragma unroll
    for (int r = 0; r < 16; r++) mx = fmaxf(mx, fmaxf(sa[0][r], sa[1][r]));
    mx = fmaxf(mx, __shfl_xor(mx, 32, 64));
    float mn = fmaxf(m_i, mx);
    float al = exp2f((m_i - mn) * 1.44269504f);
    float rs = 0.f;
#pragma unroll
    for (int tt = 0; tt < 2; tt++)
#pragma unroll
      for (int r = 0; r < 16; r++) {
        float p = exp2f((sa[tt][r] - mn) * 1.44269504f);
        sa[tt][r] = p;
        rs += p;
      }
    rs += __shfl_xor(rs, 32, 64);
    m_i = mn;
    l_i = l_i * al + rs;
#pragma unroll
    for (int vt = 0; vt < 4; vt++)
#pragma unroll
      for (int r = 0; r < 16; r++) oacc[vt][r] *= al;

    // P C-layout -> B-fragment layout, in-register.
    // P0[x] holds k = 8x+{0,1} in h=0 lanes / 8x+4+{0,1} in h=1 (x = c+4s).
    unsigned P0[8], P1[8];
#pragma unroll
    for (int x = 0; x < 8; x++) {
      int s2 = x >> 2, c4 = (x & 3) * 4;
      P0[x] = pk2(sa[s2][c4 + 0], sa[s2][c4 + 1]);
      P1[x] = pk2(sa[s2][c4 + 2], sa[s2][c4 + 3]);
    }
#pragma unroll
    for (int t = 0; t < 4; t++) {
      unsigned w0 = half ? P0[2 * t + 1] : P0[2 * t];
      unsigned y0 = half ? P0[2 * t] : P0[2 * t + 1];
      unsigned z0 = __shfl_xor(y0, 32, 64);
      unsigned w1 = half ? P1[2 * t + 1] : P1[2 * t];
      unsigned y1 = half ? P1[2 * t] : P1[2 * t + 1];
      unsigned z1 = __shfl_xor(y1, 32, 64);
      i32x4 bb;
      bb.x = (int)(half ? z0 : w0);   // j = 0,1
      bb.y = (int)(half ? z1 : w1);   // j = 2,3
      bb.z = (int)(half ? w0 : z0);   // j = 4,5
      bb.w = (int)(half ? w1 : z1);   // j = 6,7
      bf16x8 pf = __builtin_bit_cast(bf16x8, bb);
#pragma unroll
      for (int vt = 0; vt < 4; vt++) {
        bf16x8 vf = *(const bf16x8*)(vrd + vt * 32 * 64 + (((2 * t + half) ^ xr) << 3));
        oacc[vt] = __builtin_amdgcn_mfma_f32_32x32x16_bf16(vf, pf, oacc[vt], 0, 0, 0);
      }
    }
  }
  const int b = bh >> 4, h = bh & 15;
  float inv = 1.f / l_i;
  u16* orow = O + ((size_t)(b * T_ + qg)) * 2048 + h * 128 + 4 * half;
#pragma unroll
  for (int vt = 0; vt < 4; vt++)
#pragma unroll
    for (int qd = 0; qd < 4; qd++) {
      uint2 pk;
      pk.x = pk2(oacc[vt][qd * 4 + 0] * inv, oacc[vt][qd * 4 + 1] * inv);
      pk.y = pk2(oacc[vt][qd * 4 + 2] * inv, oacc[vt][qd * 4 + 3] * inv);
      *(uint2*)(orow + vt * 32 + qd * 8) = pk;
    }
}

extern "C" void kernel_launch(void* const* d_in, const int* in_sizes, int n_in,
                              void* d_out, int out_size, void* d_ws, size_t ws_size,
                              hipStream_t stream) {
  const float* x    = (const float*)d_in[0];
  const float* fcos = (const float*)d_in[1];
  const float* fsin = (const float*)d_in[2];
  const float* wqd  = (const float*)d_in[3];
  const float* qnw  = (const float*)d_in[4];
  const float* wqun = (const float*)d_in[5];
  const float* wqur = (const float*)d_in[6];
  const float* wkvd = (const float*)d_in[7];
  const float* kvnw = (const float*)d_in[8];
  const float* wkvu = (const float*)d_in[9];
  const float* qhnw = (const float*)d_in[10];
  const float* khnw = (const float*)d_in[11];
  const float* wwo  = (const float*)d_in[12];
  float* out = (float*)d_out;
  char* ws = (char*)d_ws;

  size_t off = 0;
  auto alloc = [&](size_t elems) -> u16* {
    u16* p = (u16*)(ws + off);
    off += ((elems * 2 + 255) & ~(size_t)255);
    return p;
  };
  u16* x16   = alloc(4096ull * 2048);
  u16* bqkvd = alloc(2176ull * 2048);
  u16* bqu   = alloc(3072ull * 1536);
  u16* bkvu  = alloc(4096ull * 512);
  u16* bwo   = alloc(2048ull * 2048);
  u16* cqkv  = alloc(4096ull * 2176);
  u16* cq    = alloc(4096ull * 1536);
  u16* qnr   = alloc(4096ull * 3072);
  u16* ckv   = alloc(4096ull * 512);
  u16* kvu   = alloc(4096ull * 4096);
  u16* qp    = alloc(32ull * 2048 * 192);
  u16* kp    = alloc(32ull * 2048 * 192);
  u16* vp    = alloc(32ull * 2048 * 128);
  u16* ao    = alloc(4096ull * 2048);
  if (ws_size < off) return;

  cast_f32_bf16<<<8192, 256, 0, stream>>>(x, x16, 4096 * 2048);
  castT<<<dim3(48, 64), 256, 0, stream>>>(wqd, bqkvd, 2048, 1536);
  castT<<<dim3(20, 64), 256, 0, stream>>>(wkvd, bqkvd + 1536ull * 2048, 2048, 576);
  castT<<<dim3(64, 48), 256, 0, stream>>>(wqun, bqu, 1536, 2048);
  castT<<<dim3(32, 48), 256, 0, stream>>>(wqur, bqu + 2048ull * 1536, 1536, 1024);
  castT<<<dim3(128, 16), 256, 0, stream>>>(wkvu, bkvu, 512, 4096);
  castT<<<dim3(64, 64), 256, 0, stream>>>(wwo, bwo, 2048, 2048);

  gemm_bt<<<dim3(17, 32), 256, 0, stream>>>(x16, bqkvd, cqkv, 4096, 2176, 2048, 0);
  rmsnorm_rows<<<4096, 256, 0, stream>>>(cqkv, cq, qnw, 1536, 2176, 1536);
  rmsnorm_rows<<<4096, 256, 0, stream>>>(cqkv + 1536, ckv, kvnw, 512, 2176, 512);
  gemm_bt<<<dim3(24, 32), 256, 0, stream>>>(cq, bqu, qnr, 4096, 3072, 1536, 0);
  gemm_bt<<<dim3(32, 32), 256, 0, stream>>>(ckv, bkvu, kvu, 4096, 4096, 512, 0);
  qpack<<<16384, 256, 0, stream>>>(qnr, qhnw, fcos, fsin, qp);
  kvpack<<<1024, 256, 0, stream>>>(kvu, cqkv + 1536, 2176, khnw, fcos, fsin, kp, vp);
  attn_kernel<<<256, 512, 0, stream>>>(qp, kp, vp, ao);
  gemm_bt<<<dim3(16, 32), 256, 0, stream>>>(ao, bwo, out, 4096, 2048, 2048, 1);
}